// Round 4
// baseline (167.513 us; speedup 1.0000x reference)
//
#include <hip/hip_runtime.h>

// GeodesicLoss: reference's velocity starts at exactly zero, so
// acc = -einsum(Gamma, v, v) == 0 every step and traj == outputs identically.
// Answer = mean_b ||outputs[b] - targets[b]||_2, B=524288, D=32.
// christoffel_symbols (d_in[2]) is mathematically dead.
//
// R2/R3 post-mortem: compiler sinks hoisted loads (VGPR stayed 24/32),
// defeating ILP-by-unrolling; kernel stayed latency-bound at ~3 TB/s.
// R4: pure TLP, zero loops. One float4 pair per thread (4M threads,
// 4096 blocks x 1024). Wave body issues once: 2 coalesced loads -> dot ->
// 8-lane shuffle reduce -> predicated sqrt -> leader reduce -> LDS ->
// 1 atomic/block. Latency hidden by wave turnover (16 blocks/CU queued),
// not by ILP the compiler can un-schedule.

static constexpr int B_ROWS = 524288;          // batch, D=32 -> 8 float4/row
static constexpr int NUM_F4 = B_ROWS * 8;      // 4,194,304 float4 per array
static constexpr int BLK    = 1024;
static constexpr int NBLK   = NUM_F4 / BLK;    // 4096

__global__ __launch_bounds__(1024) void geodesic_loss_kernel(
    const float4* __restrict__ o4,
    const float4* __restrict__ t4,
    float* __restrict__ out)
{
    const int idx = blockIdx.x * BLK + threadIdx.x;  // perfectly coalesced

    float4 o = o4[idx];
    float4 g = t4[idx];
    float dx = o.x - g.x;
    float dy = o.y - g.y;
    float dz = o.z - g.z;
    float dw = o.w - g.w;
    float s  = dx * dx + dy * dy + dz * dz + dw * dw;

    // sum squared-dist across the 8 lanes owning this row
    s += __shfl_xor(s, 1);
    s += __shfl_xor(s, 2);
    s += __shfl_xor(s, 4);

    // predicated sqrt: only row leaders contribute
    float d = ((threadIdx.x & 7) == 0) ? sqrtf(s) : 0.0f;

    // sum the 8 row leaders within the 64-lane wave
    d += __shfl_xor(d, 8);
    d += __shfl_xor(d, 16);
    d += __shfl_xor(d, 32);

    __shared__ float sm[16];                   // 16 waves per 1024-thr block
    const int wave = threadIdx.x >> 6;
    if ((threadIdx.x & 63) == 0) sm[wave] = d;
    __syncthreads();
    if (threadIdx.x == 0) {
        float total = 0.0f;
#pragma unroll
        for (int i = 0; i < 16; ++i) total += sm[i];
        atomicAdd(out, total * (1.0f / (float)B_ROWS));
    }
}

extern "C" void kernel_launch(void* const* d_in, const int* in_sizes, int n_in,
                              void* d_out, int out_size, void* d_ws, size_t ws_size,
                              hipStream_t stream) {
    const float4* outputs = (const float4*)d_in[0];
    const float4* targets = (const float4*)d_in[1];
    // d_in[2] (christoffel_symbols) unused: velocity is identically zero.
    float* out = (float*)d_out;

    // d_out is re-poisoned to 0xAA before every timed launch; zero it.
    hipMemsetAsync(out, 0, sizeof(float), stream);

    geodesic_loss_kernel<<<dim3(NBLK), dim3(BLK), 0, stream>>>(
        outputs, targets, out);
}

// Round 5
// 167.179 us; speedup vs baseline: 1.0020x; 1.0020x over previous
//
#include <hip/hip_runtime.h>
#include <stdint.h>

// GeodesicLoss: reference's velocity starts at exactly zero, so
// acc = -einsum(Gamma, v, v) == 0 every step and traj == outputs identically.
// Answer = mean_b ||outputs[b] - targets[b]||_2, B=524288, D=32.
// christoffel_symbols (d_in[2]) is mathematically dead.
//
// R1-R4 post-mortem: the register allocator ALWAYS serializes VGPR-staged
// loads (VGPR_Count stayed 12/24/32 regardless of source-level hoisting),
// pinning effective read BW at 2.2-3.1 TB/s, latency-bound.
// R5: stage via __builtin_amdgcn_global_load_lds — no destination VGPR, a
// side-effecting intrinsic the compiler cannot sink. 8 x 1KB/wave async
// DMAs issue back-to-back; 5 resident blocks/CU give up to 160 KB in
// flight per CU (>> ~50 KB BDP for 6 TB/s). LDS layout is contiguous
// (scatter is wave-uniform base + lane*16; no padding allowed — m104).

static constexpr int B_ROWS  = 524288;              // rows, D=32 -> 8 float4/row
static constexpr int BLK     = 256;                 // 4 waves
static constexpr int U       = 4;                   // float4 chunks per thread
static constexpr int TILE_F4 = BLK * U;             // 1024 float4 = 16 KB/array
static constexpr int NBLK    = (B_ROWS * 8) / TILE_F4;  // 4096 blocks

__global__ __launch_bounds__(BLK) void geodesic_loss_kernel(
    const float4* __restrict__ o4,
    const float4* __restrict__ t4,
    float* __restrict__ out)
{
    __shared__ float4 smO[TILE_F4];                 // 16 KB
    __shared__ float4 smG[TILE_F4];                 // 16 KB

    const int t     = threadIdx.x;
    const int wbase = t & ~63;                      // wave-uniform lane base
    const int gbase = blockIdx.x * TILE_F4;

    // Async global->LDS staging: 8 x (64 lanes x 16 B) per wave, issued
    // back-to-back with no VGPR destination to serialize on.
#pragma unroll
    for (int u = 0; u < U; ++u) {
        __builtin_amdgcn_global_load_lds(
            (const __attribute__((address_space(1))) void*)(o4 + gbase + u * BLK + t),
            (__attribute__((address_space(3))) void*)(smO + u * BLK + wbase),
            16, 0, 0);
    }
#pragma unroll
    for (int u = 0; u < U; ++u) {
        __builtin_amdgcn_global_load_lds(
            (const __attribute__((address_space(1))) void*)(t4 + gbase + u * BLK + t),
            (__attribute__((address_space(3))) void*)(smG + u * BLK + wbase),
            16, 0, 0);
    }
    __syncthreads();   // compiler drains vmcnt(0) before s_barrier

    // Compute from LDS: contiguous b128 reads (max-throughput pattern).
    float acc = 0.0f;
    const int l8 = t & 7;
#pragma unroll
    for (int u = 0; u < U; ++u) {
        float4 o = smO[u * BLK + t];
        float4 g = smG[u * BLK + t];
        float dx = o.x - g.x;
        float dy = o.y - g.y;
        float dz = o.z - g.z;
        float dw = o.w - g.w;
        float s  = dx * dx + dy * dy + dz * dz + dw * dw;
        s += __shfl_xor(s, 1);
        s += __shfl_xor(s, 2);
        s += __shfl_xor(s, 4);
        if (l8 == 0) acc += sqrtf(s);               // row leaders only
    }

    // sum the 8 row leaders within each 64-lane wave
    acc += __shfl_xor(acc, 8);
    acc += __shfl_xor(acc, 16);
    acc += __shfl_xor(acc, 32);

    __shared__ float sm[4];                         // 4 waves per block
    if ((t & 63) == 0) sm[t >> 6] = acc;
    __syncthreads();
    if (t == 0) {
        atomicAdd(out, (sm[0] + sm[1] + sm[2] + sm[3]) * (1.0f / (float)B_ROWS));
    }
}

extern "C" void kernel_launch(void* const* d_in, const int* in_sizes, int n_in,
                              void* d_out, int out_size, void* d_ws, size_t ws_size,
                              hipStream_t stream) {
    const float4* outputs = (const float4*)d_in[0];
    const float4* targets = (const float4*)d_in[1];
    // d_in[2] (christoffel_symbols) unused: velocity is identically zero.
    float* out = (float*)d_out;

    // d_out is re-poisoned to 0xAA before every timed launch; zero it.
    hipMemsetAsync(out, 0, sizeof(float), stream);

    geodesic_loss_kernel<<<dim3(NBLK), dim3(BLK), 0, stream>>>(
        outputs, targets, out);
}